// Round 6
// baseline (230.535 us; speedup 1.0000x reference)
//
#include <hip/hip_runtime.h>
#include <cstdint>

#define SRC_LEN 2048
#define BSZ     64
#define CTX     512
#define ATT     256
#define NT      16          // K tiles = CTX/BK, BK=32
#define NCHUNK  16
#define LOG2E   1.4426950408889634f
#define BBUF    16384       // 256 cols x 32 bf16 per B tile (fragment-major)

typedef unsigned short u16;
typedef unsigned int   u32;
typedef unsigned char  u8;
typedef __attribute__((ext_vector_type(8))) short bf16x8;
typedef __attribute__((ext_vector_type(4))) float f32x4;

union U4BF8 { uint4 u; bf16x8 v; };

__device__ __forceinline__ u16 f2bf(float f) {
    u32 u = __float_as_uint(f);
    u32 r = (u + 0x7FFFu + ((u >> 16) & 1u)) >> 16;
    return (u16)r;
}
__device__ __forceinline__ u32 pack2(float a, float b) {
    return (u32)f2bf(a) | ((u32)f2bf(b) << 16);
}

__device__ __forceinline__ float fast_exp2(float x) {
#if __has_builtin(__builtin_amdgcn_exp2f)
    return __builtin_amdgcn_exp2f(x);
#else
    return exp2f(x);
#endif
}
__device__ __forceinline__ float fast_rcp(float x) {
#if __has_builtin(__builtin_amdgcn_rcpf)
    return __builtin_amdgcn_rcpf(x);
#else
    return 1.0f / x;
#endif
}
__device__ __forceinline__ float fast_tanh(float x) {
    float e = fast_exp2(x * (2.0f * LOG2E));
    return 1.0f - 2.0f * fast_rcp(e + 1.0f);
}

// ---------------------------------------------------------------------------
// Kernel 1: prep — decoder projection; W_enc hi-bf16 written FRAGMENT-MAJOR
// (t, wave, n, lane -> 16B) so score's B loads are single coalesced dwordx4;
// mask dtype probe. grid 64, 256 threads
// ---------------------------------------------------------------------------
__global__ __launch_bounds__(256) void prep_kernel(
    const float* __restrict__ dec_state, const float* __restrict__ W_dec,
    const float* __restrict__ W_enc, const u8* __restrict__ mask_bytes,
    float* __restrict__ decproj, u8* __restrict__ bfrag,
    int* __restrict__ flag)
{
    const int b = blockIdx.x, t = threadIdx.x;
    __shared__ float ds[CTX];
    for (int k = t; k < CTX; k += 256) ds[k] = dec_state[b * CTX + k];
    __syncthreads();

    // decproj[b][t] = dot(dec_state[b,:], W_dec[t,:])
    const float* wrow = W_dec + t * CTX;
    float acc = 0.f;
#pragma unroll 4
    for (int k = 0; k < CTX; k += 4) {
        float4 w4 = *reinterpret_cast<const float4*>(wrow + k);
        acc += w4.x * ds[k] + w4.y * ds[k + 1] + w4.z * ds[k + 2] + w4.w * ds[k + 3];
    }
    decproj[b * ATT + t] = acc;

    // one thread per (tile, wave, n, lane): 8 consecutive k of one W_enc row
    const int gid  = b * 256 + t;          // 0..16383
    const int lane = gid & 63;
    const int n    = (gid >> 6) & 3;
    const int w    = (gid >> 8) & 3;
    const int tt   = (gid >> 10) & 15;
    const int col  = w * 64 + n * 16 + (lane & 15);   // W_enc row = att col
    const int k0   = tt * 32 + (lane >> 4) * 8;
    const float* src = W_enc + col * CTX + k0;
    float4 f0 = reinterpret_cast<const float4*>(src)[0];
    float4 f1 = reinterpret_cast<const float4*>(src)[1];
    uint4 uh;
    uh.x = pack2(f0.x, f0.y);
    uh.y = pack2(f0.z, f0.w);
    uh.z = pack2(f1.x, f1.y);
    uh.w = pack2(f1.z, f1.w);
    const int dst = tt * BBUF + w * 4096 + n * 1024 + lane * 16;  // bytes
    *reinterpret_cast<uint4*>(bfrag + dst) = uh;

    // mask dtype probe (int32 0/1 has zero bytes at idx%4!=0)
    int bad = 0;
#pragma unroll
    for (int i = 0; i < 8; ++i) {
        int idx = gid * 8 + i;
        if ((idx & 3) != 0 && mask_bytes[idx] != 0) bad = 1;
    }
    if (bad) atomicOr(flag, 1);
}

// ---------------------------------------------------------------------------
// Kernel 2: score — barrier-free ALL-ASM register pipeline.
//   A: fp32 -> VGPR via asm global_load_dwordx4, depth-3 (3 reg slots),
//      converted with v_cvt_pk_bf16_f32 at consume time.
//   B: hi-bf16 fragment-major -> VGPR via asm dwordx4, depth-2 (3 slots).
//   Per step: issue B(k+2); s_waitcnt vmcnt(24); sched_barrier(0);
//             cvt+16 MFMA; issue A(k+3).  vmcnt never 0 until the tail.
//   No LDS, no __syncthreads in the K-loop. All slots statically indexed.
// Block = one s (64 rows = all b), 4 waves x 64 att-cols. grid 2048.
// ---------------------------------------------------------------------------
__global__ __launch_bounds__(256, 2) void score_kernel(
    const float* __restrict__ hids, const u8* __restrict__ bfrag,
    const float* __restrict__ decproj, const float* __restrict__ b_enc,
    const float* __restrict__ vvec, const u8* __restrict__ maskB,
    const int* __restrict__ maskI, const int* __restrict__ flag,
    float* __restrict__ scoresT)
{
    __shared__ float spart[4][64];

    const int tid  = threadIdx.x;
    const int wave = tid >> 6, lane = tid & 63;
    const int ln15 = lane & 15, lg = lane >> 4;
    const int s    = blockIdx.x;

    f32x4 acc[4][4];
#pragma unroll
    for (int m = 0; m < 4; ++m)
#pragma unroll
        for (int n = 0; n < 4; ++n) acc[m][n] = (f32x4){0.f, 0.f, 0.f, 0.f};

    // per-lane A voffsets (bytes): row = s*64 + m*16 + ln15, k-sub = lg*8
    u32 voffA[4];
#pragma unroll
    for (int m = 0; m < 4; ++m)
        voffA[m] = (u32)(s * 64 + m * 16 + ln15) * (CTX * 4) + (u32)lg * 32;
    const u32 wb = (u32)wave * 4096 + (u32)lane * 16;   // B voffset

    uint4 aq[3][4][2];   // [slot][m][half] — literal-indexed only
    uint4 bq[3][4];      // [slot][n]

#define LA(t) do {                                                          \
    _Pragma("unroll")                                                       \
    for (int _m = 0; _m < 4; ++_m) {                                        \
        asm volatile("global_load_dwordx4 %0, %1, %2 offset:%3"             \
            : "=v"(aq[(t) % 3][_m][0])                                      \
            : "v"(voffA[_m]), "s"(hids), "i"((t) * 128));                   \
        asm volatile("global_load_dwordx4 %0, %1, %2 offset:%3"             \
            : "=v"(aq[(t) % 3][_m][1])                                      \
            : "v"(voffA[_m]), "s"(hids), "i"((t) * 128 + 16));              \
    }                                                                       \
} while (0)

#define LB(t) do {                                                          \
    const u8* _b = bfrag + (t) * BBUF;                                      \
    asm volatile("global_load_dwordx4 %0, %1, %2 offset:0"                  \
        : "=v"(bq[(t) % 3][0]) : "v"(wb), "s"(_b));                         \
    asm volatile("global_load_dwordx4 %0, %1, %2 offset:1024"               \
        : "=v"(bq[(t) % 3][1]) : "v"(wb), "s"(_b));                         \
    asm volatile("global_load_dwordx4 %0, %1, %2 offset:2048"               \
        : "=v"(bq[(t) % 3][2]) : "v"(wb), "s"(_b));                         \
    asm volatile("global_load_dwordx4 %0, %1, %2 offset:3072"               \
        : "=v"(bq[(t) % 3][3]) : "v"(wb), "s"(_b));                         \
} while (0)

#define CVT1(dst, fa, fb)                                                   \
    asm volatile("v_cvt_pk_bf16_f32 %0, %1, %2" : "=v"(dst) : "v"(fa), "v"(fb))

#define CM(t) do {                                                          \
    _Pragma("unroll")                                                       \
    for (int _m = 0; _m < 4; ++_m) {                                        \
        const uint4 _a0 = aq[(t) % 3][_m][0];                               \
        const uint4 _a1 = aq[(t) % 3][_m][1];                               \
        U4BF8 _ua;                                                          \
        CVT1(_ua.u.x, __uint_as_float(_a0.x), __uint_as_float(_a0.y));      \
        CVT1(_ua.u.y, __uint_as_float(_a0.z), __uint_as_float(_a0.w));      \
        CVT1(_ua.u.z, __uint_as_float(_a1.x), __uint_as_float(_a1.y));      \
        CVT1(_ua.u.w, __uint_as_float(_a1.z), __uint_as_float(_a1.w));      \
        _Pragma("unroll")                                                   \
        for (int _n = 0; _n < 4; ++_n) {                                    \
            U4BF8 _ub; _ub.u = bq[(t) % 3][_n];                             \
            acc[_m][_n] = __builtin_amdgcn_mfma_f32_16x16x32_bf16(          \
                _ua.v, _ub.v, acc[_m][_n], 0, 0, 0);                        \
        }                                                                   \
    }                                                                       \
} while (0)

// remaining after drain at step t: A{t+1..t+3 issued}x8 ... statically:
#define VMC(t) ((t) <= 13 ? 24 : ((t) == 14 ? 12 : 0))

#define STEP(t) do {                                                        \
    if ((t) + 2 < NT) LB((t) + 2);                                          \
    asm volatile("s_waitcnt vmcnt(%0)" :: "i"(VMC(t)) : "memory");          \
    __builtin_amdgcn_sched_barrier(0);                                      \
    CM(t);                                                                  \
    if ((t) + 3 < NT) LA((t) + 3);                                          \
} while (0)

    // prologue queue (old->new): A0, B0, A1, B1, A2
    LA(0); LB(0); LA(1); LB(1); LA(2);

    STEP(0);  STEP(1);  STEP(2);  STEP(3);
    STEP(4);  STEP(5);  STEP(6);  STEP(7);
    STEP(8);  STEP(9);  STEP(10); STEP(11);
    STEP(12); STEP(13); STEP(14); STEP(15);

#undef LA
#undef LB
#undef CVT1
#undef CM
#undef VMC
#undef STEP

    // ---- epilogue: x = enc + b_enc + decproj; partial = sum tanh(x)*v ----
    float bE[4], vE[4];
#pragma unroll
    for (int n = 0; n < 4; ++n) {
        const int a = wave * 64 + n * 16 + ln15;
        bE[n] = b_enc[a];
        vE[n] = vvec[a];
    }
    const float* dpb = decproj + wave * 64 + ln15;
#pragma unroll
    for (int m = 0; m < 4; ++m) {
#pragma unroll
        for (int j = 0; j < 4; ++j) {
            const int rl = m * 16 + lg * 4 + j;     // = b index
            float partial = 0.f;
#pragma unroll
            for (int n = 0; n < 4; ++n) {
                float x = acc[m][n][j] + bE[n] + dpb[rl * ATT + n * 16];
                partial += fast_tanh(x) * vE[n];
            }
            partial += __shfl_xor(partial, 1);
            partial += __shfl_xor(partial, 2);
            partial += __shfl_xor(partial, 4);
            partial += __shfl_xor(partial, 8);
            if (ln15 == 0) spart[wave][rl] = partial;
        }
    }
    __syncthreads();

    if (tid < 64) {
        const int b = tid;
        float sc = spart[0][b] + spart[1][b] + spart[2][b] + spart[3][b];
        const int isByte = *flag;
        int mv;
        if (isByte) mv = (int)maskB[s * BSZ + b];
        else        mv = maskI[s * BSZ + b];
        scoresT[b * SRC_LEN + s] = (mv != 0) ? -1e30f : sc;
    }
}

// ---------------------------------------------------------------------------
// Kernel 3: softmax over s per batch column b. grid 64, 256 threads.
// ---------------------------------------------------------------------------
__global__ __launch_bounds__(256) void softmax_kernel(
    const float* __restrict__ scoresT, float* __restrict__ wT,
    float* __restrict__ outNorm)
{
    const int b = blockIdx.x, t = threadIdx.x;
    const int wv = t >> 6, ln = t & 63;
    __shared__ float red[8];

    float v[8];
    float m = -1e30f;
#pragma unroll
    for (int i = 0; i < 8; ++i) {
        v[i] = scoresT[b * SRC_LEN + i * 256 + t];
        m = fmaxf(m, v[i]);
    }
#pragma unroll
    for (int o = 1; o < 64; o <<= 1) m = fmaxf(m, __shfl_xor(m, o));
    if (ln == 0) red[wv] = m;
    __syncthreads();
    m = fmaxf(fmaxf(red[0], red[1]), fmaxf(red[2], red[3]));

    float e[8];
    float ssum = 0.f;
#pragma unroll
    for (int i = 0; i < 8; ++i) {
        e[i] = fast_exp2((v[i] - m) * LOG2E);
        ssum += e[i];
    }
#pragma unroll
    for (int o = 1; o < 64; o <<= 1) ssum += __shfl_xor(ssum, o);
    if (ln == 0) red[4 + wv] = ssum;
    __syncthreads();
    ssum = red[4] + red[5] + red[6] + red[7];

    const float inv = 1.0f / ssum;
#pragma unroll
    for (int i = 0; i < 8; ++i) {
        const float w = e[i] * inv;
        const int sIdx = i * 256 + t;
        wT[b * SRC_LEN + sIdx] = w;
        outNorm[sIdx * BSZ + b] = w;
    }
}

// ---------------------------------------------------------------------------
// Kernel 4: context partial sums. grid (64 b, 16 s-chunks), 128 threads.
// ---------------------------------------------------------------------------
__global__ __launch_bounds__(128) void context_partial(
    const float* __restrict__ hids, const float* __restrict__ wT,
    float* __restrict__ partials)
{
    const int b = blockIdx.x, chunk = blockIdx.y, t = threadIdx.x;
    float4 acc = {0.f, 0.f, 0.f, 0.f};
    const int s0 = chunk * (SRC_LEN / NCHUNK);
#pragma unroll 4
    for (int s = s0; s < s0 + (SRC_LEN / NCHUNK); ++s) {
        const float w = wT[b * SRC_LEN + s];
        if (w != 0.0f) {
            float4 h = reinterpret_cast<const float4*>(hids + (size_t)(s * BSZ + b) * CTX)[t];
            acc.x += w * h.x; acc.y += w * h.y; acc.z += w * h.z; acc.w += w * h.w;
        }
    }
    reinterpret_cast<float4*>(partials + (size_t)(chunk * BSZ + b) * CTX)[t] = acc;
}

// ---------------------------------------------------------------------------
// Kernel 5: reduce partials -> context output. grid 64, 128 threads.
// ---------------------------------------------------------------------------
__global__ __launch_bounds__(128) void context_reduce(
    const float* __restrict__ partials, float* __restrict__ ctx)
{
    const int b = blockIdx.x, t = threadIdx.x;
    float4 acc = {0.f, 0.f, 0.f, 0.f};
#pragma unroll
    for (int c = 0; c < NCHUNK; ++c) {
        float4 p = reinterpret_cast<const float4*>(partials + (size_t)(c * BSZ + b) * CTX)[t];
        acc.x += p.x; acc.y += p.y; acc.z += p.z; acc.w += p.w;
    }
    reinterpret_cast<float4*>(ctx + (size_t)b * CTX)[t] = acc;
}

// ---------------------------------------------------------------------------
extern "C" void kernel_launch(void* const* d_in, const int* in_sizes, int n_in,
                              void* d_out, int out_size, void* d_ws, size_t ws_size,
                              hipStream_t stream)
{
    const float* dec_state = (const float*)d_in[0];
    const float* hids      = (const float*)d_in[1];
    const void*  mask_raw  = d_in[2];
    const float* W_enc     = (const float*)d_in[3];
    const float* b_enc     = (const float*)d_in[4];
    const float* W_dec     = (const float*)d_in[5];
    const float* vvec      = (const float*)d_in[6];

    float* out_ctx  = (float*)d_out;                 // [64][512]
    float* out_norm = out_ctx + BSZ * CTX;           // [2048][64]

    char* ws = (char*)d_ws;
    float* decproj  = (float*)(ws);                  //  64*256*4   = 65536
    u8*    bfrag    = (u8*)(ws + 65536);             // 16*16384    = 262144
    float* scoresT  = (float*)(ws + 589824);         // 64*2048*4   = 524288
    float* wT       = (float*)(ws + 1114112);        // 524288
    float* partials = (float*)(ws + 1638400);        // 16*64*512*4 = 2097152
    int*   flag     = (int*)(ws + 3735552);

    hipMemsetAsync(flag, 0, 4, stream);

    prep_kernel<<<64, 256, 0, stream>>>(dec_state, W_dec, W_enc,
                                        (const u8*)mask_raw, decproj, bfrag, flag);

    score_kernel<<<SRC_LEN, 256, 0, stream>>>(
        hids, bfrag, decproj, b_enc, vvec,
        (const u8*)mask_raw, (const int*)mask_raw, flag, scoresT);

    softmax_kernel<<<BSZ, 256, 0, stream>>>(scoresT, wT, out_norm);

    context_partial<<<dim3(BSZ, NCHUNK), 128, 0, stream>>>(hids, wT, partials);

    context_reduce<<<BSZ, 128, 0, stream>>>(partials, out_ctx);
}

// Round 7
// 148.225 us; speedup vs baseline: 1.5553x; 1.5553x over previous
//
#include <hip/hip_runtime.h>
#include <cstdint>

#define SRC_LEN 2048
#define BSZ     64
#define CTX     512
#define ATT     256
#define NT      16          // K tiles = CTX/BK, BK=32
#define NCHUNK  32
#define LOG2E   1.4426950408889634f
#define ABUF    8192        // 64 rows x 32 fp32 per A tile
#define BBUF    16384       // 256 cols x 32 bf16 per B tile (fragment-major)

typedef unsigned short u16;
typedef unsigned int   u32;
typedef unsigned char  u8;
typedef __attribute__((ext_vector_type(8))) short bf16x8;
typedef __attribute__((ext_vector_type(4))) float f32x4;

union U4BF8 { uint4 u; bf16x8 v; };

__device__ __forceinline__ u16 f2bf(float f) {
    u32 u = __float_as_uint(f);
    u32 r = (u + 0x7FFFu + ((u >> 16) & 1u)) >> 16;
    return (u16)r;
}
__device__ __forceinline__ u32 pack2(float a, float b) {
    return (u32)f2bf(a) | ((u32)f2bf(b) << 16);
}

__device__ __forceinline__ float fast_exp2(float x) {
#if __has_builtin(__builtin_amdgcn_exp2f)
    return __builtin_amdgcn_exp2f(x);
#else
    return exp2f(x);
#endif
}
__device__ __forceinline__ float fast_rcp(float x) {
#if __has_builtin(__builtin_amdgcn_rcpf)
    return __builtin_amdgcn_rcpf(x);
#else
    return 1.0f / x;
#endif
}
__device__ __forceinline__ float fast_tanh(float x) {
    float e = fast_exp2(x * (2.0f * LOG2E));
    return 1.0f - 2.0f * fast_rcp(e + 1.0f);
}

// async global->LDS, 16B per lane; LDS dest = wave-uniform base + lane*16,
// global source is PER-LANE (pre-swizzle the source, keep LDS linear).
typedef const __attribute__((address_space(1))) unsigned char ga_u8;
typedef __attribute__((address_space(3))) unsigned char ls_u8;
__device__ __forceinline__ void gl_lds16(const void* g, void* l) {
    __builtin_amdgcn_global_load_lds((ga_u8*)g, (ls_u8*)l, 16, 0, 0);
}

// ---------------------------------------------------------------------------
// Kernel 1: prep — decoder projection; W_enc hi-bf16 written FRAGMENT-MAJOR
// (t, wave, n, lane -> 16B) so score's B loads are single coalesced dwordx4;
// mask dtype probe. grid 64, 256 threads
// ---------------------------------------------------------------------------
__global__ __launch_bounds__(256) void prep_kernel(
    const float* __restrict__ dec_state, const float* __restrict__ W_dec,
    const float* __restrict__ W_enc, const u8* __restrict__ mask_bytes,
    float* __restrict__ decproj, u8* __restrict__ bfrag,
    int* __restrict__ flag)
{
    const int b = blockIdx.x, t = threadIdx.x;
    __shared__ float ds[CTX];
    for (int k = t; k < CTX; k += 256) ds[k] = dec_state[b * CTX + k];
    __syncthreads();

    // decproj[b][t] = dot(dec_state[b,:], W_dec[t,:])
    const float* wrow = W_dec + t * CTX;
    float acc = 0.f;
#pragma unroll 4
    for (int k = 0; k < CTX; k += 4) {
        float4 w4 = *reinterpret_cast<const float4*>(wrow + k);
        acc += w4.x * ds[k] + w4.y * ds[k + 1] + w4.z * ds[k + 2] + w4.w * ds[k + 3];
    }
    decproj[b * ATT + t] = acc;

    // one thread per (tile, wave, n, lane): 8 consecutive k of one W_enc row
    const int gid  = b * 256 + t;          // 0..16383
    const int lane = gid & 63;
    const int n    = (gid >> 6) & 3;
    const int w    = (gid >> 8) & 3;
    const int tt   = (gid >> 10) & 15;
    const int col  = w * 64 + n * 16 + (lane & 15);   // W_enc row = att col
    const int k0   = tt * 32 + (lane >> 4) * 8;
    const float* src = W_enc + col * CTX + k0;
    float4 f0 = reinterpret_cast<const float4*>(src)[0];
    float4 f1 = reinterpret_cast<const float4*>(src)[1];
    uint4 uh;
    uh.x = pack2(f0.x, f0.y);
    uh.y = pack2(f0.z, f0.w);
    uh.z = pack2(f1.x, f1.y);
    uh.w = pack2(f1.z, f1.w);
    const int dst = tt * BBUF + w * 4096 + n * 1024 + lane * 16;  // bytes
    *reinterpret_cast<uint4*>(bfrag + dst) = uh;

    // mask dtype probe (int32 0/1 has zero bytes at idx%4!=0)
    int bad = 0;
#pragma unroll
    for (int i = 0; i < 8; ++i) {
        int idx = gid * 8 + i;
        if ((idx & 3) != 0 && mask_bytes[idx] != 0) bad = 1;
    }
    if (bad) atomicOr(flag, 1);
}

// ---------------------------------------------------------------------------
// Kernel 2: score — deep counted-vmcnt pipeline (T3/T4/T5):
//   A: fp32 via global_load_lds, 4 LDS buffers, staged 3 steps ahead,
//      XOR-swizzled via per-lane source addr (rule #21); cvt_pk at consume.
//   B: hi-bf16 fragment-major, asm dwordx4 -> 3-slot reg queue, 2 ahead.
//   Step: s_waitcnt vmcnt(8) -> s_barrier -> sched_barrier -> issue
//   LB(t+2),LA(t+3) -> setprio(1) 16 MFMA setprio(0).
//   Steady queue after wait: [A(t+1),B(t+1),A(t+2)] = 8 loads in flight.
// Block = one s (64 rows = all b), 4 waves x 64 att-cols. grid 2048.
// ---------------------------------------------------------------------------
__global__ __launch_bounds__(256, 3) void score_kernel(
    const float* __restrict__ hids, const u8* __restrict__ bfrag,
    const float* __restrict__ decproj, const float* __restrict__ b_enc,
    const float* __restrict__ vvec, const u8* __restrict__ maskB,
    const int* __restrict__ maskI, const int* __restrict__ flag,
    float* __restrict__ scoresT)
{
    __shared__ __align__(16) char smA[4 * ABUF];   // 32 KB
    __shared__ float spart[4][64];

    const int tid  = threadIdx.x;
    const int wave = tid >> 6, lane = tid & 63;
    const int ln15 = lane & 15, lg = lane >> 4;
    const int s    = blockIdx.x;
    const int rs   = ln15 & 7;            // A read-side swizzle (const/thread)
    const int p0   = (lg * 2) ^ rs;
    const int p1   = (lg * 2 + 1) ^ rs;

    f32x4 acc[4][4];
#pragma unroll
    for (int m = 0; m < 4; ++m)
#pragma unroll
        for (int n = 0; n < 4; ++n) acc[m][n] = (f32x4){0.f, 0.f, 0.f, 0.f};

    // A stage: 8 KB/step = 2 gl_lds insts/wave; swizzle on the SOURCE side.
    auto stageA = [&](int t, int buf) {
#pragma unroll
        for (int i = 0; i < 2; ++i) {
            const int g   = (wave * 2 + i) * 64 + lane;   // 16B chunk 0..511
            const int row = g >> 3;
            const int cl  = (g & 7) ^ (row & 7);
            const char* src = (const char*)(hids + (size_t)(s * 64 + row) * CTX + t * 32) + cl * 16;
            gl_lds16(src, smA + buf * ABUF + (wave * 2 + i) * 1024);
        }
    };

    const u32 wb = (u32)wave * 4096 + (u32)lane * 16;   // B voffset base
    uint4 bq[3][4];   // [slot = tile%3][n] — literal-indexed only

#define LB(t) do {                                                          \
    const u32 _voff = wb + (u32)(t) * BBUF;                                 \
    asm volatile("global_load_dwordx4 %0, %1, %2 offset:0"                  \
        : "=v"(bq[(t) % 3][0]) : "v"(_voff), "s"(bfrag));                   \
    asm volatile("global_load_dwordx4 %0, %1, %2 offset:1024"               \
        : "=v"(bq[(t) % 3][1]) : "v"(_voff), "s"(bfrag));                   \
    asm volatile("global_load_dwordx4 %0, %1, %2 offset:2048"               \
        : "=v"(bq[(t) % 3][2]) : "v"(_voff), "s"(bfrag));                   \
    asm volatile("global_load_dwordx4 %0, %1, %2 offset:3072"               \
        : "=v"(bq[(t) % 3][3]) : "v"(_voff), "s"(bfrag));                   \
} while (0)

#define CVT1(dst, fa, fb)                                                   \
    asm volatile("v_cvt_pk_bf16_f32 %0, %1, %2" : "=v"(dst) : "v"(fa), "v"(fb))

#define CM(t) do {                                                          \
    const char* _ab = smA + ((t) % 4) * ABUF;                               \
    bf16x8 _bf[4];                                                          \
    _Pragma("unroll")                                                       \
    for (int _n = 0; _n < 4; ++_n) {                                        \
        U4BF8 _u; _u.u = bq[(t) % 3][_n]; _bf[_n] = _u.v;                   \
    }                                                                       \
    _Pragma("unroll")                                                       \
    for (int _m = 0; _m < 4; ++_m) {                                        \
        const char* _ar = _ab + (_m * 16 + ln15) * 128;                     \
        float4 _a0 = *reinterpret_cast<const float4*>(_ar + p0 * 16);       \
        float4 _a1 = *reinterpret_cast<const float4*>(_ar + p1 * 16);       \
        U4BF8 _ua;                                                          \
        CVT1(_ua.u.x, _a0.x, _a0.y);                                        \
        CVT1(_ua.u.y, _a0.z, _a0.w);                                        \
        CVT1(_ua.u.z, _a1.x, _a1.y);                                        \
        CVT1(_ua.u.w, _a1.z, _a1.w);                                        \
        _Pragma("unroll")                                                   \
        for (int _n = 0; _n < 4; ++_n)                                      \
            acc[_m][_n] = __builtin_amdgcn_mfma_f32_16x16x32_bf16(          \
                _ua.v, _bf[_n], acc[_m][_n], 0, 0, 0);                      \
    }                                                                       \
} while (0)

// outstanding entering step t: [A(t),B(t),A(t+1),B(t+1),A(t+2)] = 14 (steady)
#define VMC(t) ((t) <= 13 ? 8 : ((t) == 14 ? 6 : 0))

#define STEP(t) do {                                                        \
    asm volatile("s_waitcnt vmcnt(%0)" :: "i"(VMC(t)) : "memory");          \
    __builtin_amdgcn_s_barrier();                                           \
    __builtin_amdgcn_sched_barrier(0);                                      \
    if ((t) + 2 < NT) LB((t) + 2);                                          \
    if ((t) + 3 < NT) stageA((t) + 3, ((t) + 3) % 4);                       \
    __builtin_amdgcn_s_setprio(1);                                          \
    CM(t);                                                                  \
    __builtin_amdgcn_s_setprio(0);                                          \
} while (0)

    // prologue queue (old->new): A0, B0, A1, B1, A2
    stageA(0, 0); LB(0); stageA(1, 1); LB(1); stageA(2, 2);

    STEP(0);  STEP(1);  STEP(2);  STEP(3);
    STEP(4);  STEP(5);  STEP(6);  STEP(7);
    STEP(8);  STEP(9);  STEP(10); STEP(11);
    STEP(12); STEP(13); STEP(14); STEP(15);

#undef LB
#undef CVT1
#undef CM
#undef VMC
#undef STEP

    // ---- epilogue: x = enc + b_enc + decproj; partial = sum tanh(x)*v ----
    float bE[4], vE[4];
#pragma unroll
    for (int n = 0; n < 4; ++n) {
        const int a = wave * 64 + n * 16 + ln15;
        bE[n] = b_enc[a];
        vE[n] = vvec[a];
    }
    const float* dpb = decproj + wave * 64 + ln15;
#pragma unroll
    for (int m = 0; m < 4; ++m) {
#pragma unroll
        for (int j = 0; j < 4; ++j) {
            const int rl = m * 16 + lg * 4 + j;     // = b index
            float partial = 0.f;
#pragma unroll
            for (int n = 0; n < 4; ++n) {
                float x = acc[m][n][j] + bE[n] + dpb[rl * ATT + n * 16];
                partial += fast_tanh(x) * vE[n];
            }
            partial += __shfl_xor(partial, 1);
            partial += __shfl_xor(partial, 2);
            partial += __shfl_xor(partial, 4);
            partial += __shfl_xor(partial, 8);
            if (ln15 == 0) spart[wave][rl] = partial;
        }
    }
    __syncthreads();

    if (tid < 64) {
        const int b = tid;
        float sc = spart[0][b] + spart[1][b] + spart[2][b] + spart[3][b];
        const int isByte = *flag;
        int mv;
        if (isByte) mv = (int)maskB[s * BSZ + b];
        else        mv = maskI[s * BSZ + b];
        scoresT[b * SRC_LEN + s] = (mv != 0) ? -1e30f : sc;
    }
}

// ---------------------------------------------------------------------------
// Kernel 3: softmax over s per batch column b. grid 64, 256 threads.
// ---------------------------------------------------------------------------
__global__ __launch_bounds__(256) void softmax_kernel(
    const float* __restrict__ scoresT, float* __restrict__ wT,
    float* __restrict__ outNorm)
{
    const int b = blockIdx.x, t = threadIdx.x;
    const int wv = t >> 6, ln = t & 63;
    __shared__ float red[8];

    float v[8];
    float m = -1e30f;
#pragma unroll
    for (int i = 0; i < 8; ++i) {
        v[i] = scoresT[b * SRC_LEN + i * 256 + t];
        m = fmaxf(m, v[i]);
    }
#pragma unroll
    for (int o = 1; o < 64; o <<= 1) m = fmaxf(m, __shfl_xor(m, o));
    if (ln == 0) red[wv] = m;
    __syncthreads();
    m = fmaxf(fmaxf(red[0], red[1]), fmaxf(red[2], red[3]));

    float e[8];
    float ssum = 0.f;
#pragma unroll
    for (int i = 0; i < 8; ++i) {
        e[i] = fast_exp2((v[i] - m) * LOG2E);
        ssum += e[i];
    }
#pragma unroll
    for (int o = 1; o < 64; o <<= 1) ssum += __shfl_xor(ssum, o);
    if (ln == 0) red[4 + wv] = ssum;
    __syncthreads();
    ssum = red[4] + red[5] + red[6] + red[7];

    const float inv = 1.0f / ssum;
#pragma unroll
    for (int i = 0; i < 8; ++i) {
        const float w = e[i] * inv;
        const int sIdx = i * 256 + t;
        wT[b * SRC_LEN + sIdx] = w;
        outNorm[sIdx * BSZ + b] = w;
    }
}

// ---------------------------------------------------------------------------
// Kernel 4: context partial sums. grid (64 b, 32 s-chunks), 128 threads.
// 4 independent accumulators break the FMA dep chain; unrolled loads.
// ---------------------------------------------------------------------------
__global__ __launch_bounds__(128) void context_partial(
    const float* __restrict__ hids, const float* __restrict__ wT,
    float* __restrict__ partials)
{
    const int b = blockIdx.x, chunk = blockIdx.y, t = threadIdx.x;
    float4 a0 = {0.f, 0.f, 0.f, 0.f}, a1 = a0, a2 = a0, a3 = a0;
    const int s0 = chunk * (SRC_LEN / NCHUNK);   // 64 s per chunk
#pragma unroll 4
    for (int s = s0; s < s0 + (SRC_LEN / NCHUNK); s += 4) {
        const float w0 = wT[b * SRC_LEN + s];
        const float w1 = wT[b * SRC_LEN + s + 1];
        const float w2 = wT[b * SRC_LEN + s + 2];
        const float w3 = wT[b * SRC_LEN + s + 3];
        if (w0 != 0.0f) {
            float4 h = reinterpret_cast<const float4*>(hids + (size_t)((s) * BSZ + b) * CTX)[t];
            a0.x += w0 * h.x; a0.y += w0 * h.y; a0.z += w0 * h.z; a0.w += w0 * h.w;
        }
        if (w1 != 0.0f) {
            float4 h = reinterpret_cast<const float4*>(hids + (size_t)((s + 1) * BSZ + b) * CTX)[t];
            a1.x += w1 * h.x; a1.y += w1 * h.y; a1.z += w1 * h.z; a1.w += w1 * h.w;
        }
        if (w2 != 0.0f) {
            float4 h = reinterpret_cast<const float4*>(hids + (size_t)((s + 2) * BSZ + b) * CTX)[t];
            a2.x += w2 * h.x; a2.y += w2 * h.y; a2.z += w2 * h.z; a2.w += w2 * h.w;
        }
        if (w3 != 0.0f) {
            float4 h = reinterpret_cast<const float4*>(hids + (size_t)((s + 3) * BSZ + b) * CTX)[t];
            a3.x += w3 * h.x; a3.y += w3 * h.y; a3.z += w3 * h.z; a3.w += w3 * h.w;
        }
    }
    float4 acc;
    acc.x = (a0.x + a1.x) + (a2.x + a3.x);
    acc.y = (a0.y + a1.y) + (a2.y + a3.y);
    acc.z = (a0.z + a1.z) + (a2.z + a3.z);
    acc.w = (a0.w + a1.w) + (a2.w + a3.w);
    reinterpret_cast<float4*>(partials + (size_t)(chunk * BSZ + b) * CTX)[t] = acc;
}

// ---------------------------------------------------------------------------
// Kernel 5: reduce partials -> context output. grid 64, 128 threads.
// ---------------------------------------------------------------------------
__global__ __launch_bounds__(128) void context_reduce(
    const float* __restrict__ partials, float* __restrict__ ctx)
{
    const int b = blockIdx.x, t = threadIdx.x;
    float4 acc = {0.f, 0.f, 0.f, 0.f};
#pragma unroll
    for (int c = 0; c < NCHUNK; ++c) {
        float4 p = reinterpret_cast<const float4*>(partials + (size_t)(c * BSZ + b) * CTX)[t];
        acc.x += p.x; acc.y += p.y; acc.z += p.z; acc.w += p.w;
    }
    reinterpret_cast<float4*>(ctx + (size_t)b * CTX)[t] = acc;
}

// ---------------------------------------------------------------------------
extern "C" void kernel_launch(void* const* d_in, const int* in_sizes, int n_in,
                              void* d_out, int out_size, void* d_ws, size_t ws_size,
                              hipStream_t stream)
{
    const float* dec_state = (const float*)d_in[0];
    const float* hids      = (const float*)d_in[1];
    const void*  mask_raw  = d_in[2];
    const float* W_enc     = (const float*)d_in[3];
    const float* b_enc     = (const float*)d_in[4];
    const float* W_dec     = (const float*)d_in[5];
    const float* vvec      = (const float*)d_in[6];

    float* out_ctx  = (float*)d_out;                 // [64][512]
    float* out_norm = out_ctx + BSZ * CTX;           // [2048][64]

    char* ws = (char*)d_ws;
    float* decproj  = (float*)(ws);                  //  64*256*4   = 65536
    u8*    bfrag    = (u8*)(ws + 65536);             // 16*16384    = 262144
    float* scoresT  = (float*)(ws + 589824);         // 64*2048*4   = 524288
    float* wT       = (float*)(ws + 1114112);        // 524288
    float* partials = (float*)(ws + 1638400);        // 32*64*512*4 = 4194304
    int*   flag     = (int*)(ws + 8388608);

    hipMemsetAsync(flag, 0, 4, stream);

    prep_kernel<<<64, 256, 0, stream>>>(dec_state, W_dec, W_enc,
                                        (const u8*)mask_raw, decproj, bfrag, flag);

    score_kernel<<<SRC_LEN, 256, 0, stream>>>(
        hids, bfrag, decproj, b_enc, vvec,
        (const u8*)mask_raw, (const int*)mask_raw, flag, scoresT);

    softmax_kernel<<<BSZ, 256, 0, stream>>>(scoresT, wT, out_norm);

    context_partial<<<dim3(BSZ, NCHUNK), 128, 0, stream>>>(hids, wT, partials);

    context_reduce<<<BSZ, 128, 0, stream>>>(partials, out_ctx);
}

// Round 8
// 131.368 us; speedup vs baseline: 1.7549x; 1.1283x over previous
//
#include <hip/hip_runtime.h>
#include <cstdint>

#define SRC_LEN 2048
#define BSZ     64
#define CTX     512
#define ATT     256
#define NT      8           // K steps, BK=64
#define NCHUNK  32
#define LOG2E   1.4426950408889634f
#define ABUF    16384       // 64 rows x 64 fp32 per A step-tile
#define BTILE   16384       // old 32-k B tile bytes (fragment-major)

typedef unsigned short u16;
typedef unsigned int   u32;
typedef unsigned char  u8;
typedef __attribute__((ext_vector_type(8))) short bf16x8;
typedef __attribute__((ext_vector_type(4))) float f32x4;

union U4BF8 { uint4 u; bf16x8 v; };

__device__ __forceinline__ u16 f2bf(float f) {
    u32 u = __float_as_uint(f);
    u32 r = (u + 0x7FFFu + ((u >> 16) & 1u)) >> 16;
    return (u16)r;
}
__device__ __forceinline__ u32 pack2(float a, float b) {
    return (u32)f2bf(a) | ((u32)f2bf(b) << 16);
}

__device__ __forceinline__ float fast_exp2(float x) {
#if __has_builtin(__builtin_amdgcn_exp2f)
    return __builtin_amdgcn_exp2f(x);
#else
    return exp2f(x);
#endif
}
__device__ __forceinline__ float fast_rcp(float x) {
#if __has_builtin(__builtin_amdgcn_rcpf)
    return __builtin_amdgcn_rcpf(x);
#else
    return 1.0f / x;
#endif
}
__device__ __forceinline__ float fast_tanh(float x) {
    float e = fast_exp2(x * (2.0f * LOG2E));
    return 1.0f - 2.0f * fast_rcp(e + 1.0f);
}

// async global->LDS, 16B/lane; LDS dest = wave-uniform base + lane*16,
// global source is PER-LANE (pre-swizzle the source, keep LDS linear).
typedef const __attribute__((address_space(1))) unsigned char ga_u8;
typedef __attribute__((address_space(3))) unsigned char ls_u8;
__device__ __forceinline__ void gl_lds16(const void* g, void* l) {
    __builtin_amdgcn_global_load_lds((ga_u8*)g, (ls_u8*)l, 16, 0, 0);
}

// ---------------------------------------------------------------------------
// Kernel 1: prep — decoder projection; W_enc hi-bf16 written FRAGMENT-MAJOR
// (t32, wave, n, lane -> 16B); mask dtype probe. grid 64, 256 threads
// ---------------------------------------------------------------------------
__global__ __launch_bounds__(256) void prep_kernel(
    const float* __restrict__ dec_state, const float* __restrict__ W_dec,
    const float* __restrict__ W_enc, const u8* __restrict__ mask_bytes,
    float* __restrict__ decproj, u8* __restrict__ bfrag,
    int* __restrict__ flag)
{
    const int b = blockIdx.x, t = threadIdx.x;
    __shared__ float ds[CTX];
    for (int k = t; k < CTX; k += 256) ds[k] = dec_state[b * CTX + k];
    __syncthreads();

    const float* wrow = W_dec + t * CTX;
    float acc = 0.f;
#pragma unroll 4
    for (int k = 0; k < CTX; k += 4) {
        float4 w4 = *reinterpret_cast<const float4*>(wrow + k);
        acc += w4.x * ds[k] + w4.y * ds[k + 1] + w4.z * ds[k + 2] + w4.w * ds[k + 3];
    }
    decproj[b * ATT + t] = acc;

    // one thread per (tile32, wave, n, lane): 8 consecutive k of one W_enc row
    const int gid  = b * 256 + t;          // 0..16383
    const int lane = gid & 63;
    const int n    = (gid >> 6) & 3;
    const int w    = (gid >> 8) & 3;
    const int tt   = (gid >> 10) & 15;
    const int col  = w * 64 + n * 16 + (lane & 15);
    const int k0   = tt * 32 + (lane >> 4) * 8;
    const float* src = W_enc + col * CTX + k0;
    float4 f0 = reinterpret_cast<const float4*>(src)[0];
    float4 f1 = reinterpret_cast<const float4*>(src)[1];
    uint4 uh;
    uh.x = pack2(f0.x, f0.y);
    uh.y = pack2(f0.z, f0.w);
    uh.z = pack2(f1.x, f1.y);
    uh.w = pack2(f1.z, f1.w);
    const int dst = tt * BTILE + w * 4096 + n * 1024 + lane * 16;
    *reinterpret_cast<uint4*>(bfrag + dst) = uh;

    // mask dtype probe (int32 0/1 has zero bytes at idx%4!=0)
    int bad = 0;
#pragma unroll
    for (int i = 0; i < 8; ++i) {
        int idx = gid * 8 + i;
        if ((idx & 3) != 0 && mask_bytes[idx] != 0) bad = 1;
    }
    if (bad) atomicOr(flag, 1);
}

// ---------------------------------------------------------------------------
// Kernel 2: score — BK=64 counted-vmcnt pipeline (8 steps).
//   A: fp32 via global_load_lds, 3 x 16KB LDS bufs, staged 2 steps ahead,
//      4-bit XOR source-side swizzle; masked rows' source CLAMPED to row 0
//      (same issue count -> static vmcnt stays valid; HBM dedupe ~25%).
//   B: hi-bf16 fragment-major, asm dwordx4 -> 2-slot reg queue (8/slot).
//   Step: s_waitcnt vmcnt(4) -> s_barrier -> sched_barrier -> LB(t+1),
//         stageA(t+2) -> setprio(1) 32 MFMA setprio(0).
// Block = one s (64 rows = all b), 4 waves x 64 att-cols. grid 2048.
// ---------------------------------------------------------------------------
__global__ __launch_bounds__(256, 3) void score_kernel(
    const float* __restrict__ hids, const u8* __restrict__ bfrag,
    const float* __restrict__ decproj, const float* __restrict__ b_enc,
    const float* __restrict__ vvec, const u8* __restrict__ maskB,
    const int* __restrict__ maskI, const int* __restrict__ flag,
    float* __restrict__ scoresT)
{
    __shared__ __align__(16) char smA[3 * ABUF];   // 48 KB
    __shared__ float spart[4][64];

    const int tid  = threadIdx.x;
    const int wave = tid >> 6, lane = tid & 63;
    const int ln15 = lane & 15, lg = lane >> 4;
    const int s    = blockIdx.x;
    const int isByte = *flag;

    f32x4 acc[4][4];
#pragma unroll
    for (int m = 0; m < 4; ++m)
#pragma unroll
        for (int n = 0; n < 4; ++n) acc[m][n] = (f32x4){0.f, 0.f, 0.f, 0.f};

    // ---- per-lane A source pointers (mask-clamped, pre-swizzled) ----
    // i-th stage inst: g = (wave*4+i)*64+lane; row = g>>4; c_phys = g&15.
    // source logical chunk cl = c_phys ^ (row&15); masked row -> row 0.
    const char* srcA[4];
#pragma unroll
    for (int i = 0; i < 4; ++i) {
        const int row = wave * 16 + i * 4 + lg;
        const int cl  = (ln15) ^ (row & 15);
        int mv;
        if (isByte) mv = (int)maskB[s * BSZ + row];
        else        mv = maskI[s * BSZ + row];
        const int row_eff = (mv != 0) ? 0 : row;
        srcA[i] = (const char*)(hids + (size_t)(s * 64 + row_eff) * CTX) + cl * 16;
    }

    auto stageA = [&](int t, int buf) {
#pragma unroll
        for (int i = 0; i < 4; ++i)
            gl_lds16(srcA[i] + t * 256, smA + buf * ABUF + (wave * 4 + i) * 1024);
    };

    const u32 wb = (u32)wave * 4096 + (u32)lane * 16;   // B voffset base
    uint4 bq[2][8];   // [slot=t%2][kk*4+n] — literal-indexed only

#define LB(t) do {                                                          \
    const u8* _b0 = bfrag + (t) * 2 * BTILE;                                \
    const u8* _b1 = _b0 + BTILE;                                            \
    asm volatile("global_load_dwordx4 %0, %1, %2 offset:0"                  \
        : "=v"(bq[(t) % 2][0]) : "v"(wb), "s"(_b0));                        \
    asm volatile("global_load_dwordx4 %0, %1, %2 offset:1024"               \
        : "=v"(bq[(t) % 2][1]) : "v"(wb), "s"(_b0));                        \
    asm volatile("global_load_dwordx4 %0, %1, %2 offset:2048"               \
        : "=v"(bq[(t) % 2][2]) : "v"(wb), "s"(_b0));                        \
    asm volatile("global_load_dwordx4 %0, %1, %2 offset:3072"               \
        : "=v"(bq[(t) % 2][3]) : "v"(wb), "s"(_b0));                        \
    asm volatile("global_load_dwordx4 %0, %1, %2 offset:0"                  \
        : "=v"(bq[(t) % 2][4]) : "v"(wb), "s"(_b1));                        \
    asm volatile("global_load_dwordx4 %0, %1, %2 offset:1024"               \
        : "=v"(bq[(t) % 2][5]) : "v"(wb), "s"(_b1));                        \
    asm volatile("global_load_dwordx4 %0, %1, %2 offset:2048"               \
        : "=v"(bq[(t) % 2][6]) : "v"(wb), "s"(_b1));                        \
    asm volatile("global_load_dwordx4 %0, %1, %2 offset:3072"               \
        : "=v"(bq[(t) % 2][7]) : "v"(wb), "s"(_b1));                        \
} while (0)

#define CVT1(dst, fa, fb)                                                   \
    asm volatile("v_cvt_pk_bf16_f32 %0, %1, %2" : "=v"(dst) : "v"(fa), "v"(fb))

#define CM(t) do {                                                          \
    const char* _ab = smA + ((t) % 3) * ABUF;                               \
    _Pragma("unroll")                                                       \
    for (int _kk = 0; _kk < 2; ++_kk) {                                     \
        bf16x8 _bf[4];                                                      \
        _Pragma("unroll")                                                   \
        for (int _n = 0; _n < 4; ++_n) {                                    \
            U4BF8 _u; _u.u = bq[(t) % 2][_kk * 4 + _n]; _bf[_n] = _u.v;     \
        }                                                                   \
        _Pragma("unroll")                                                   \
        for (int _m = 0; _m < 4; ++_m) {                                    \
            const char* _ar = _ab + (_m * 16 + ln15) * 256;                 \
            const int _p0 = (_kk * 8 + lg * 2) ^ ln15;                      \
            const int _p1 = (_kk * 8 + lg * 2 + 1) ^ ln15;                  \
            float4 _a0 = *reinterpret_cast<const float4*>(_ar + _p0 * 16);  \
            float4 _a1 = *reinterpret_cast<const float4*>(_ar + _p1 * 16);  \
            U4BF8 _ua;                                                      \
            CVT1(_ua.u.x, _a0.x, _a0.y);                                    \
            CVT1(_ua.u.y, _a0.z, _a0.w);                                    \
            CVT1(_ua.u.z, _a1.x, _a1.y);                                    \
            CVT1(_ua.u.w, _a1.z, _a1.w);                                    \
            _Pragma("unroll")                                               \
            for (int _n = 0; _n < 4; ++_n)                                  \
                acc[_m][_n] = __builtin_amdgcn_mfma_f32_16x16x32_bf16(      \
                    _ua.v, _bf[_n], acc[_m][_n], 0, 0, 0);                  \
        }                                                                   \
    }                                                                       \
} while (0)

// outstanding entering step t (steady): A(t)4, B(t)8, A(t+1)4 -> wait 4
#define VMC(t) ((t) < NT - 1 ? 4 : 0)

#define STEP(t) do {                                                        \
    asm volatile("s_waitcnt vmcnt(%0)" :: "i"(VMC(t)) : "memory");          \
    __builtin_amdgcn_s_barrier();                                           \
    __builtin_amdgcn_sched_barrier(0);                                      \
    if ((t) + 1 < NT) LB((t) + 1);                                          \
    if ((t) + 2 < NT) stageA((t) + 2, ((t) + 2) % 3);                       \
    __builtin_amdgcn_s_setprio(1);                                          \
    CM(t);                                                                  \
    __builtin_amdgcn_s_setprio(0);                                          \
} while (0)

    // prologue queue (old->new): A0x4, B0x8, A1x4
    stageA(0, 0); LB(0); stageA(1, 1);

    STEP(0); STEP(1); STEP(2); STEP(3);
    STEP(4); STEP(5); STEP(6); STEP(7);

#undef LB
#undef CVT1
#undef CM
#undef VMC
#undef STEP

    // ---- epilogue: x = enc + b_enc + decproj; partial = sum tanh(x)*v ----
    float bE[4], vE[4];
#pragma unroll
    for (int n = 0; n < 4; ++n) {
        const int a = wave * 64 + n * 16 + ln15;
        bE[n] = b_enc[a];
        vE[n] = vvec[a];
    }
    const float* dpb = decproj + wave * 64 + ln15;
#pragma unroll
    for (int m = 0; m < 4; ++m) {
#pragma unroll
        for (int j = 0; j < 4; ++j) {
            const int rl = m * 16 + lg * 4 + j;     // = b index
            float partial = 0.f;
#pragma unroll
            for (int n = 0; n < 4; ++n) {
                float x = acc[m][n][j] + bE[n] + dpb[rl * ATT + n * 16];
                partial += fast_tanh(x) * vE[n];
            }
            partial += __shfl_xor(partial, 1);
            partial += __shfl_xor(partial, 2);
            partial += __shfl_xor(partial, 4);
            partial += __shfl_xor(partial, 8);
            if (ln15 == 0) spart[wave][rl] = partial;
        }
    }
    __syncthreads();

    if (tid < 64) {
        const int b = tid;
        float sc = spart[0][b] + spart[1][b] + spart[2][b] + spart[3][b];
        int mv;
        if (isByte) mv = (int)maskB[s * BSZ + b];
        else        mv = maskI[s * BSZ + b];
        scoresT[b * SRC_LEN + s] = (mv != 0) ? -1e30f : sc;
    }
}

// ---------------------------------------------------------------------------
// Kernel 3: softmax over s per batch column b. grid 64, 256 threads.
// ---------------------------------------------------------------------------
__global__ __launch_bounds__(256) void softmax_kernel(
    const float* __restrict__ scoresT, float* __restrict__ wT,
    float* __restrict__ outNorm)
{
    const int b = blockIdx.x, t = threadIdx.x;
    const int wv = t >> 6, ln = t & 63;
    __shared__ float red[8];

    float v[8];
    float m = -1e30f;
#pragma unroll
    for (int i = 0; i < 8; ++i) {
        v[i] = scoresT[b * SRC_LEN + i * 256 + t];
        m = fmaxf(m, v[i]);
    }
#pragma unroll
    for (int o = 1; o < 64; o <<= 1) m = fmaxf(m, __shfl_xor(m, o));
    if (ln == 0) red[wv] = m;
    __syncthreads();
    m = fmaxf(fmaxf(red[0], red[1]), fmaxf(red[2], red[3]));

    float e[8];
    float ssum = 0.f;
#pragma unroll
    for (int i = 0; i < 8; ++i) {
        e[i] = fast_exp2((v[i] - m) * LOG2E);
        ssum += e[i];
    }
#pragma unroll
    for (int o = 1; o < 64; o <<= 1) ssum += __shfl_xor(ssum, o);
    if (ln == 0) red[4 + wv] = ssum;
    __syncthreads();
    ssum = red[4] + red[5] + red[6] + red[7];

    const float inv = 1.0f / ssum;
#pragma unroll
    for (int i = 0; i < 8; ++i) {
        const float w = e[i] * inv;
        const int sIdx = i * 256 + t;
        wT[b * SRC_LEN + sIdx] = w;
        outNorm[sIdx * BSZ + b] = w;
    }
}

// ---------------------------------------------------------------------------
// Kernel 4: context partial sums. grid (64 b, 32 s-chunks), 128 threads.
// ---------------------------------------------------------------------------
__global__ __launch_bounds__(128) void context_partial(
    const float* __restrict__ hids, const float* __restrict__ wT,
    float* __restrict__ partials)
{
    const int b = blockIdx.x, chunk = blockIdx.y, t = threadIdx.x;
    float4 a0 = {0.f, 0.f, 0.f, 0.f}, a1 = a0, a2 = a0, a3 = a0;
    const int s0 = chunk * (SRC_LEN / NCHUNK);   // 64 s per chunk
#pragma unroll 4
    for (int s = s0; s < s0 + (SRC_LEN / NCHUNK); s += 4) {
        const float w0 = wT[b * SRC_LEN + s];
        const float w1 = wT[b * SRC_LEN + s + 1];
        const float w2 = wT[b * SRC_LEN + s + 2];
        const float w3 = wT[b * SRC_LEN + s + 3];
        if (w0 != 0.0f) {
            float4 h = reinterpret_cast<const float4*>(hids + (size_t)((s) * BSZ + b) * CTX)[t];
            a0.x += w0 * h.x; a0.y += w0 * h.y; a0.z += w0 * h.z; a0.w += w0 * h.w;
        }
        if (w1 != 0.0f) {
            float4 h = reinterpret_cast<const float4*>(hids + (size_t)((s + 1) * BSZ + b) * CTX)[t];
            a1.x += w1 * h.x; a1.y += w1 * h.y; a1.z += w1 * h.z; a1.w += w1 * h.w;
        }
        if (w2 != 0.0f) {
            float4 h = reinterpret_cast<const float4*>(hids + (size_t)((s + 2) * BSZ + b) * CTX)[t];
            a2.x += w2 * h.x; a2.y += w2 * h.y; a2.z += w2 * h.z; a2.w += w2 * h.w;
        }
        if (w3 != 0.0f) {
            float4 h = reinterpret_cast<const float4*>(hids + (size_t)((s + 3) * BSZ + b) * CTX)[t];
            a3.x += w3 * h.x; a3.y += w3 * h.y; a3.z += w3 * h.z; a3.w += w3 * h.w;
        }
    }
    float4 acc;
    acc.x = (a0.x + a1.x) + (a2.x + a3.x);
    acc.y = (a0.y + a1.y) + (a2.y + a3.y);
    acc.z = (a0.z + a1.z) + (a2.z + a3.z);
    acc.w = (a0.w + a1.w) + (a2.w + a3.w);
    reinterpret_cast<float4*>(partials + (size_t)(chunk * BSZ + b) * CTX)[t] = acc;
}

// ---------------------------------------------------------------------------
// Kernel 5: reduce partials -> context output. grid 64, 128 threads.
// ---------------------------------------------------------------------------
__global__ __launch_bounds__(128) void context_reduce(
    const float* __restrict__ partials, float* __restrict__ ctx)
{
    const int b = blockIdx.x, t = threadIdx.x;
    float4 acc = {0.f, 0.f, 0.f, 0.f};
#pragma unroll
    for (int c = 0; c < NCHUNK; ++c) {
        float4 p = reinterpret_cast<const float4*>(partials + (size_t)(c * BSZ + b) * CTX)[t];
        acc.x += p.x; acc.y += p.y; acc.z += p.z; acc.w += p.w;
    }
    reinterpret_cast<float4*>(ctx + (size_t)b * CTX)[t] = acc;
}

// ---------------------------------------------------------------------------
extern "C" void kernel_launch(void* const* d_in, const int* in_sizes, int n_in,
                              void* d_out, int out_size, void* d_ws, size_t ws_size,
                              hipStream_t stream)
{
    const float* dec_state = (const float*)d_in[0];
    const float* hids      = (const float*)d_in[1];
    const void*  mask_raw  = d_in[2];
    const float* W_enc     = (const float*)d_in[3];
    const float* b_enc     = (const float*)d_in[4];
    const float* W_dec     = (const float*)d_in[5];
    const float* vvec      = (const float*)d_in[6];

    float* out_ctx  = (float*)d_out;                 // [64][512]
    float* out_norm = out_ctx + BSZ * CTX;           // [2048][64]

    char* ws = (char*)d_ws;
    float* decproj  = (float*)(ws);                  //  64*256*4   = 65536
    u8*    bfrag    = (u8*)(ws + 65536);             // 16*16384    = 262144
    float* scoresT  = (float*)(ws + 589824);         // 64*2048*4   = 524288
    float* wT       = (float*)(ws + 1114112);        // 524288
    float* partials = (float*)(ws + 1638400);        // 32*64*512*4 = 4194304
    int*   flag     = (int*)(ws + 8388608);

    hipMemsetAsync(flag, 0, 4, stream);

    prep_kernel<<<64, 256, 0, stream>>>(dec_state, W_dec, W_enc,
                                        (const u8*)mask_raw, decproj, bfrag, flag);

    score_kernel<<<SRC_LEN, 256, 0, stream>>>(
        hids, bfrag, decproj, b_enc, vvec,
        (const u8*)mask_raw, (const int*)mask_raw, flag, scoresT);

    softmax_kernel<<<BSZ, 256, 0, stream>>>(scoresT, wT, out_norm);

    context_partial<<<dim3(BSZ, NCHUNK), 128, 0, stream>>>(hids, wT, partials);

    context_reduce<<<BSZ, 128, 0, stream>>>(partials, out_ctx);
}